// Round 10
// baseline (144.895 us; speedup 1.0000x reference)
//
#include <hip/hip_runtime.h>
#include <math.h>

#define BB_   2
#define CIN_  256
#define NTOK_ 2048
#define FF_   512
#define COUT_ 256
#define NH_   8
#define DH_   64
#define HW_   128
#define BNEPS_ 1e-5f
#define SCALE_LOG2_ 0.09016844005556021f  /* log2(e)/16, folded into K at qkv */

typedef __attribute__((ext_vector_type(8))) short short8;
typedef __attribute__((ext_vector_type(4))) short bfx4;
typedef __attribute__((ext_vector_type(4))) float f32x4;

#if __has_builtin(__builtin_amdgcn_mfma_f32_16x16x16_bf16)
#define MFMA16(a, b, c) __builtin_amdgcn_mfma_f32_16x16x16_bf16(a, b, c, 0, 0, 0)
#else
#define MFMA16(a, b, c) __builtin_amdgcn_mfma_f32_16x16x16bf16_1k(a, b, c, 0, 0, 0)
#endif

__device__ inline unsigned short f2bf(float f) {
  union { float f; unsigned u; } v; v.f = f;
  unsigned r = (v.u + 0x7FFF + ((v.u >> 16) & 1)) >> 16;  // RNE
  return (unsigned short)r;
}

// async global->LDS DMA, 16 B per lane; LDS dest = wave-uniform base + lane*16
__device__ __forceinline__ void dma16(const unsigned short* g, unsigned short* l) {
  __builtin_amdgcn_global_load_lds(
      (const __attribute__((address_space(1))) void*)g,
      (__attribute__((address_space(3))) void*)l, 16, 0, 0);
}

// ---------------------------------------------------------------------------
// Kernel 1 (R9 form): QKV projection reading x/W fp32 directly; in-kernel
// transpose+bf16 convert (bit-identical to old prep); R8 coalesced epilogue.
// ---------------------------------------------------------------------------
__global__ __launch_bounds__(256, 3) void qkv_kernel(
    const float* __restrict__ x, const float* __restrict__ WK,
    const float* __restrict__ WQ, const float* __restrict__ WV,
    unsigned short* __restrict__ Kb, unsigned short* __restrict__ Qb,
    unsigned short* __restrict__ Vt) {
  __shared__ unsigned short Wsh[128 * 72];
  __shared__ unsigned short Xsh[64 * 72];
  __shared__ float T[64 * 65];
  const int tid = threadIdx.x;
  const int lane = tid & 63, w = tid >> 6;
  const int lx = lane & 15, q = lane >> 4;
  const int wm = w >> 1, wn = w & 1;
  const int n0 = blockIdx.x * 64;
  const int f0 = blockIdx.y * 128;
  const int b = blockIdx.z / 3, which = blockIdx.z % 3;
  const float* Wb = which == 0 ? WK : which == 1 ? WQ : WV;

  const int srow = tid >> 3;          // 0..31
  const int soff = (tid & 7) * 8;     // 0..56
  const float* Wg = Wb + (size_t)(f0 + srow) * CIN_ + soff;
  const int tc = tid >> 4;            // 0..15
  const int tn = (tid & 15) * 4;

  float4 wr[4][2], xr[4];
#pragma unroll
  for (int r = 0; r < 4; ++r) {
    wr[r][0] = *(const float4*)(Wg + (size_t)(32 * r) * CIN_);
    wr[r][1] = *(const float4*)(Wg + (size_t)(32 * r) * CIN_ + 4);
  }
#pragma unroll
  for (int p = 0; p < 4; ++p)
    xr[p] = *(const float4*)(x + (size_t)(b * CIN_ + tc + 16 * p) * NTOK_ + n0 + tn);

  f32x4 acc[4][2];
#pragma unroll
  for (int i = 0; i < 4; ++i)
#pragma unroll
    for (int j = 0; j < 2; ++j) acc[i][j] = (f32x4){0.f, 0.f, 0.f, 0.f};

  for (int kk = 0; kk < 4; ++kk) {
    __syncthreads();   // (A) previous MFMA reads done; T/Wsh writable
#pragma unroll
    for (int p = 0; p < 4; ++p) {
      const int row = tc + 16 * p;
      T[row * 65 + tn + 0] = xr[p].x; T[row * 65 + tn + 1] = xr[p].y;
      T[row * 65 + tn + 2] = xr[p].z; T[row * 65 + tn + 3] = xr[p].w;
    }
#pragma unroll
    for (int r = 0; r < 4; ++r) {
      unsigned short u[8];
      u[0] = f2bf(wr[r][0].x); u[1] = f2bf(wr[r][0].y);
      u[2] = f2bf(wr[r][0].z); u[3] = f2bf(wr[r][0].w);
      u[4] = f2bf(wr[r][1].x); u[5] = f2bf(wr[r][1].y);
      u[6] = f2bf(wr[r][1].z); u[7] = f2bf(wr[r][1].w);
      *(uint4*)(Wsh + (srow + 32 * r) * 72 + soff) = *(uint4*)u;
    }
    __syncthreads();   // (B) T ready
#pragma unroll
    for (int p = 0; p < 2; ++p) {
      const int idx = tid + 256 * p;
      const int nl = idx >> 3, c8 = (idx & 7) * 8;
      unsigned short u[8];
#pragma unroll
      for (int i = 0; i < 8; ++i) u[i] = f2bf(T[(c8 + i) * 65 + nl]);
      *(uint4*)(Xsh + nl * 72 + c8) = *(uint4*)u;
    }
    if (kk < 3) {
      const int c0 = (kk + 1) * 64;
#pragma unroll
      for (int r = 0; r < 4; ++r) {
        wr[r][0] = *(const float4*)(Wg + (size_t)(32 * r) * CIN_ + c0);
        wr[r][1] = *(const float4*)(Wg + (size_t)(32 * r) * CIN_ + c0 + 4);
      }
#pragma unroll
      for (int p = 0; p < 4; ++p)
        xr[p] = *(const float4*)(x + (size_t)(b * CIN_ + c0 + tc + 16 * p) * NTOK_ + n0 + tn);
    }
    __syncthreads();   // (C) Xsh/Wsh ready
    short8 xF[2][2];
#pragma unroll
    for (int i = 0; i < 2; ++i) {
      xF[i][0] = *(const short8*)(Xsh + (32 * wn + 16 * i + lx) * 72 + q * 8);
      xF[i][1] = *(const short8*)(Xsh + (32 * wn + 16 * i + lx) * 72 + 32 + q * 8);
    }
    if (which < 2) {
#pragma unroll
      for (int i = 0; i < 4; ++i) {
        const short8 w0 = *(const short8*)(Wsh + (64 * wm + 16 * i + lx) * 72 + q * 8);
        const short8 w1 = *(const short8*)(Wsh + (64 * wm + 16 * i + lx) * 72 + 32 + q * 8);
#pragma unroll
        for (int j = 0; j < 2; ++j) {
          acc[i][j] = __builtin_amdgcn_mfma_f32_16x16x32_bf16(w0, xF[j][0], acc[i][j], 0, 0, 0);
          acc[i][j] = __builtin_amdgcn_mfma_f32_16x16x32_bf16(w1, xF[j][1], acc[i][j], 0, 0, 0);
        }
      }
    } else {
#pragma unroll
      for (int jf = 0; jf < 4; ++jf) {
        const short8 w0 = *(const short8*)(Wsh + (64 * wm + 16 * jf + lx) * 72 + q * 8);
        const short8 w1 = *(const short8*)(Wsh + (64 * wm + 16 * jf + lx) * 72 + 32 + q * 8);
#pragma unroll
        for (int i = 0; i < 2; ++i) {
          acc[jf][i] = __builtin_amdgcn_mfma_f32_16x16x32_bf16(xF[i][0], w0, acc[jf][i], 0, 0, 0);
          acc[jf][i] = __builtin_amdgcn_mfma_f32_16x16x32_bf16(xF[i][1], w1, acc[jf][i], 0, 0, 0);
        }
      }
    }
  }

  // ---- coalesced epilogue (R8)
  __syncthreads();

  if (which < 2) {
    const float sc = (which == 0) ? SCALE_LOG2_ : 1.0f;
#pragma unroll
    for (int i = 0; i < 4; ++i)
#pragma unroll
      for (int j = 0; j < 2; ++j) {
        const int row = wm * 64 + 32 * wn + 16 * j + lx;
        const int d0 = 16 * i + 4 * q;
        ushort4 u;
        u.x = f2bf(acc[i][j][0] * sc); u.y = f2bf(acc[i][j][1] * sc);
        u.z = f2bf(acc[i][j][2] * sc); u.w = f2bf(acc[i][j][3] * sc);
        *(ushort4*)(Wsh + row * 72 + d0) = u;
      }
  } else {
#pragma unroll
    for (int jf = 0; jf < 4; ++jf)
#pragma unroll
      for (int i = 0; i < 2; ++i) {
        const int row = wm * 64 + 16 * jf + lx;
        const int nc = 32 * wn + 16 * i + 4 * q;
        ushort4 u;
        u.x = f2bf(acc[jf][i][0]); u.y = f2bf(acc[jf][i][1]);
        u.z = f2bf(acc[jf][i][2]); u.w = f2bf(acc[jf][i][3]);
        *(ushort4*)(Wsh + row * 72 + nc) = u;
      }
  }
  __syncthreads();

  const int h0 = f0 >> 6;
  if (which < 2) {
    unsigned short* Y = (which == 0 ? Kb : Qb);
#pragma unroll
    for (int p = 0; p < 4; ++p) {
      const int idx = tid + 256 * p;
      const int row = idx >> 3;
      const int c = (idx & 7) * 8;
      const uint4 val = *(const uint4*)(Wsh + row * 72 + c);
      *(uint4*)(Y + ((size_t)((b * NH_ + h0 + (row >> 6)) * NTOK_ + n0 + (row & 63))) * DH_ + c) = val;
    }
  } else {
#pragma unroll
    for (int p = 0; p < 4; ++p) {
      const int idx = tid + 256 * p;
      const int row = idx >> 3;
      const int c = (idx & 7) * 8;
      const uint4 val = *(const uint4*)(Wsh + row * 72 + c);
      *(uint4*)(Vt + ((size_t)((b * NH_ + h0 + (row >> 6)) * DH_ + (row & 63))) * NTOK_ + n0 + c) = val;
    }
  }
}

// ---------------------------------------------------------------------------
// Kernel 2: block-causal attention — S^T trick, DMA dbuf, XCD grouping, LPT.
// ---------------------------------------------------------------------------
__global__ __launch_bounds__(256, 2) void attn_kernel(
    const unsigned short* __restrict__ Kb, const unsigned short* __restrict__ Qb,
    const unsigned short* __restrict__ Vt, unsigned short* __restrict__ Ob) {
  __shared__ __align__(16) unsigned short Qbuf[2][8192];
  __shared__ __align__(16) unsigned short Vbuf[2][8192];

  const int tid = threadIdx.x;
  const int lane = tid & 63;
  const int w = tid >> 6;
  const int lx = lane & 15;
  const int g = lane >> 4;

  const int bid = blockIdx.x;
  const int xcd = bid & 7;
  const int k = bid >> 3;
  const int bh = xcd * 2 + (k & 1);
  const int u = k >> 1;
  const int iblk = (u < 16) ? (31 - u) : (u - 16);
  const int h = bh & 7, b = bh >> 3;
  const int i0 = iblk * 64;
  const int njt = (iblk >> 1) + 1;

  const size_t bhs = (size_t)b * NH_ + h;
  const unsigned short* Kg = Kb + bhs * (size_t)NTOK_ * DH_ + (size_t)i0 * DH_;
  const unsigned short* Qg = Qb + bhs * (size_t)NTOK_ * DH_;
  const unsigned short* Vg = Vt + bhs * (size_t)DH_ * NTOK_;

  auto stage = [&](int buf, int j0) {
#pragma unroll
    for (int cc = 0; cc < 4; ++cc) {
      const int chunk = 4 * w + cc;
      {  // Q
        const int row = chunk * 8 + (lane >> 3);
        const int grp = (lane & 7) ^ (row & 7);
        dma16(Qg + (size_t)(j0 + row) * DH_ + grp * 8, &Qbuf[buf][chunk * 512]);
      }
      {  // V
        const int row = chunk * 4 + (lane >> 4);
        const int grp = (lane & 15) ^ (row & 7);
        dma16(Vg + (size_t)row * NTOK_ + j0 + grp * 8, &Vbuf[buf][chunk * 512]);
      }
    }
  };

  const short8 aK0 = *(const short8*)(Kg + (16 * w + lx) * DH_ + g * 8);
  const short8 aK1 = *(const short8*)(Kg + (16 * w + lx) * DH_ + 32 + g * 8);

  f32x4 o[4];
#pragma unroll
  for (int t = 0; t < 4; ++t) o[t] = (f32x4){0.f, 0.f, 0.f, 0.f};
  float rs = 0.f;

  const int fr0 = ((g ^ (lx & 7)) << 3);
  const int fr1 = (((4 + g) ^ (lx & 7)) << 3);

  stage(0, 0);
  __syncthreads();

  int cur = 0;
  for (int jt = 0; jt < njt; ++jt) {
    if (jt + 1 < njt) stage(cur ^ 1, (jt + 1) * 128);

    const unsigned short* Qs = Qbuf[cur];
    const unsigned short* Vs = Vbuf[cur];

    f32x4 sa[8];
#pragma unroll
    for (int s = 0; s < 8; ++s) {
      const int row = 16 * s + lx;
      const short8 a0 = *(const short8*)(Qs + row * 64 + fr0);
      const short8 a1 = *(const short8*)(Qs + row * 64 + fr1);
      sa[s] = (f32x4){0.f, 0.f, 0.f, 0.f};
      sa[s] = __builtin_amdgcn_mfma_f32_16x16x32_bf16(a0, aK0, sa[s], 0, 0, 0);
      sa[s] = __builtin_amdgcn_mfma_f32_16x16x32_bf16(a1, aK1, sa[s], 0, 0, 0);
    }

#pragma unroll
    for (int s = 0; s < 8; ++s) {
      const float p0 = __builtin_amdgcn_exp2f(sa[s][0]);
      const float p1 = __builtin_amdgcn_exp2f(sa[s][1]);
      const float p2 = __builtin_amdgcn_exp2f(sa[s][2]);
      const float p3 = __builtin_amdgcn_exp2f(sa[s][3]);
      rs += (p0 + p1) + (p2 + p3);
      union { unsigned u[2]; bfx4 v; } pk;
      pk.u[0] = (__builtin_bit_cast(unsigned, p0) >> 16) |
                (__builtin_bit_cast(unsigned, p1) & 0xFFFF0000u);
      pk.u[1] = (__builtin_bit_cast(unsigned, p2) >> 16) |
                (__builtin_bit_cast(unsigned, p3) & 0xFFFF0000u);
      const int jgrp = 2 * s + (g >> 1);
      const int joff = (g & 1) << 2;
#pragma unroll
      for (int t = 0; t < 4; ++t) {
        const int row = 16 * t + lx;
        const bfx4 va = *(const bfx4*)(Vs + row * 128 +
                                       ((jgrp ^ (row & 7)) << 3) + joff);
        o[t] = MFMA16(va, pk.v, o[t]);
      }
    }

    __syncthreads();
    cur ^= 1;
  }

  rs += __shfl_xor(rs, 16);
  rs += __shfl_xor(rs, 32);
  const float invl = 1.0f / rs;
  const int n = i0 + 16 * w + lx;
#pragma unroll
  for (int t = 0; t < 4; ++t) {
    ushort4 uo;
    uo.x = f2bf(o[t][0] * invl); uo.y = f2bf(o[t][1] * invl);
    uo.z = f2bf(o[t][2] * invl); uo.w = f2bf(o[t][3] * invl);
    *(ushort4*)(Ob + ((size_t)(b * NTOK_ + n)) * FF_ + h * 64 + 16 * t + 4 * g) = uo;
  }
}

// ---------------------------------------------------------------------------
// Kernel 3 (R10): proj + bias + ReLU + skip -> out, THEN fused BatchNorm via
// ticket/last-arrival: every block fetch_adds a counter after its stores
// (ACQ_REL -> release of stores); tickets 0..255 exit, tickets 256..511 spin
// (RELAXED + s_sleep, one ACQUIRE load on exit) until all 512 arrived, then
// each normalizes channel (ticket-256) with the ORIGINAL 256-thread bn body.
// Deadlock-safe without co-residency: all blocks increment BEFORE any spin.
// ---------------------------------------------------------------------------
__global__ __launch_bounds__(256, 2) void proj_bn_kernel(
    const unsigned short* __restrict__ Ob, const float* __restrict__ Wo,
    const float* __restrict__ bo, const float* __restrict__ x,
    float* __restrict__ out, const float* __restrict__ gamma,
    const float* __restrict__ beta, unsigned* __restrict__ ctr) {
  __shared__ unsigned short Osh[32 * 72];
  __shared__ unsigned short Wsh[64 * 72];
  __shared__ float red[8];
  __shared__ unsigned tksh;
  const int tid = threadIdx.x;
  const int lane = tid & 63, w = tid >> 6;
  const int lx = lane & 15, q = lane >> 4;
  const int n0 = blockIdx.x * 32;
  const int o0 = blockIdx.y * 64;
  const int b = blockIdx.z;

  const int srow = tid >> 3;
  const int soff = (tid & 7) * 8;
  const unsigned short* Og = Ob + ((size_t)(b * NTOK_ + n0 + srow)) * FF_ + soff;
  const float* Wg = Wo + (size_t)(o0 + srow) * FF_ + soff;

  uint4 orr;
  float4 wrr[2][2];
  orr = *(const uint4*)(Og);
#pragma unroll
  for (int r = 0; r < 2; ++r) {
    wrr[r][0] = *(const float4*)(Wg + (size_t)(32 * r) * FF_);
    wrr[r][1] = *(const float4*)(Wg + (size_t)(32 * r) * FF_ + 4);
  }

  f32x4 acc[2];
#pragma unroll
  for (int i = 0; i < 2; ++i) acc[i] = (f32x4){0.f, 0.f, 0.f, 0.f};

  for (int kk = 0; kk < 8; ++kk) {
    __syncthreads();
    *(uint4*)(Osh + srow * 72 + soff) = orr;
#pragma unroll
    for (int r = 0; r < 2; ++r) {
      unsigned short u[8];
      u[0] = f2bf(wrr[r][0].x); u[1] = f2bf(wrr[r][0].y);
      u[2] = f2bf(wrr[r][0].z); u[3] = f2bf(wrr[r][0].w);
      u[4] = f2bf(wrr[r][1].x); u[5] = f2bf(wrr[r][1].y);
      u[6] = f2bf(wrr[r][1].z); u[7] = f2bf(wrr[r][1].w);
      *(uint4*)(Wsh + (srow + 32 * r) * 72 + soff) = *(uint4*)u;
    }
    if (kk < 7) {
      const int c0 = (kk + 1) * 64;
      orr = *(const uint4*)(Og + c0);
#pragma unroll
      for (int r = 0; r < 2; ++r) {
        wrr[r][0] = *(const float4*)(Wg + (size_t)(32 * r) * FF_ + c0);
        wrr[r][1] = *(const float4*)(Wg + (size_t)(32 * r) * FF_ + c0 + 4);
      }
    }
    __syncthreads();
    short8 aF[2][2], bF[2];
#pragma unroll
    for (int i = 0; i < 2; ++i) {
      aF[i][0] = *(const short8*)(Osh + (16 * i + lx) * 72 + q * 8);
      aF[i][1] = *(const short8*)(Osh + (16 * i + lx) * 72 + 32 + q * 8);
    }
    bF[0] = *(const short8*)(Wsh + (16 * w + lx) * 72 + q * 8);
    bF[1] = *(const short8*)(Wsh + (16 * w + lx) * 72 + 32 + q * 8);
#pragma unroll
    for (int i = 0; i < 2; ++i) {
      acc[i] = __builtin_amdgcn_mfma_f32_16x16x32_bf16(aF[i][0], bF[0], acc[i], 0, 0, 0);
      acc[i] = __builtin_amdgcn_mfma_f32_16x16x32_bf16(aF[i][1], bF[1], acc[i], 0, 0, 0);
    }
  }

  {
    const int o = o0 + 16 * w + lx;
    const float bias = bo[o];
#pragma unroll
    for (int i = 0; i < 2; ++i) {
      const int n = n0 + 16 * i + 4 * q;
      const float4 xv = *(const float4*)(x + ((size_t)(b * CIN_ + o)) * NTOK_ + n);
      float4 v;
      v.x = fmaxf(acc[i][0] + bias, 0.f) + xv.x;
      v.y = fmaxf(acc[i][1] + bias, 0.f) + xv.y;
      v.z = fmaxf(acc[i][2] + bias, 0.f) + xv.z;
      v.w = fmaxf(acc[i][3] + bias, 0.f) + xv.w;
      *(float4*)(out + ((size_t)(b * COUT_ + o)) * NTOK_ + n) = v;
    }
  }

  // ---- ticket: arrival AFTER stores (ACQ_REL releases them) ----
  __syncthreads();
  if (tid == 0) {
    tksh = __hip_atomic_fetch_add(ctr, 1u, __ATOMIC_ACQ_REL,
                                  __HIP_MEMORY_SCOPE_AGENT);
  }
  __syncthreads();
  const unsigned ticket = tksh;
  if (ticket < 256) return;          // early arrivals exit, free the CU

  if (tid == 0) {
    while (__hip_atomic_load(ctr, __ATOMIC_RELAXED,
                             __HIP_MEMORY_SCOPE_AGENT) < 512u) {
      __builtin_amdgcn_s_sleep(4);
    }
    (void)__hip_atomic_load(ctr, __ATOMIC_ACQUIRE, __HIP_MEMORY_SCOPE_AGENT);
  }
  __syncthreads();

  // ---- BatchNorm for channel c = ticket-256 (original 256-thread body) ----
  const int c = (int)ticket - 256;

  float4 v[2][2];
  float s = 0.f, s2 = 0.f;
#pragma unroll
  for (int bb = 0; bb < BB_; ++bb) {
    float* base = out + ((size_t)(bb * COUT_ + c)) * NTOK_;
#pragma unroll
    for (int p = 0; p < 2; ++p) {
      const float4 t = *(const float4*)(base + 4 * tid + p * 1024);
      v[bb][p] = t;
      s += t.x + t.y + t.z + t.w;
      s2 += t.x * t.x + t.y * t.y + t.z * t.z + t.w * t.w;
    }
  }
#pragma unroll
  for (int off = 32; off >= 1; off >>= 1) {
    s += __shfl_xor(s, off);
    s2 += __shfl_xor(s2, off);
  }
  if (lane == 0) { red[w] = s; red[4 + w] = s2; }
  __syncthreads();
  const float S = red[0] + red[1] + red[2] + red[3];
  const float S2 = red[4] + red[5] + red[6] + red[7];
  const float inv = 1.0f / (float)(BB_ * NTOK_);
  const float mean = S * inv;
  const float var = S2 * inv - mean * mean;
  const float sc = rsqrtf(var + BNEPS_) * gamma[c];
  const float bt = beta[c];
#pragma unroll
  for (int bb = 0; bb < BB_; ++bb) {
    float* base = out + ((size_t)(bb * COUT_ + c)) * NTOK_;
#pragma unroll
    for (int p = 0; p < 2; ++p) {
      float4 t = v[bb][p];
      t.x = (t.x - mean) * sc + bt;
      t.y = (t.y - mean) * sc + bt;
      t.z = (t.z - mean) * sc + bt;
      t.w = (t.w - mean) * sc + bt;
      *(float4*)(base + 4 * tid + p * 1024) = t;
    }
  }
}

extern "C" void kernel_launch(void* const* d_in, const int* in_sizes, int n_in,
                              void* d_out, int out_size, void* d_ws, size_t ws_size,
                              hipStream_t stream) {
  (void)in_sizes; (void)n_in; (void)out_size; (void)ws_size;
  const float* x = (const float*)d_in[0];
  const float* WK = (const float*)d_in[1];
  const float* WQ = (const float*)d_in[2];
  const float* WV = (const float*)d_in[3];
  const float* Wo = (const float*)d_in[4];
  const float* bo = (const float*)d_in[5];
  const float* gamma = (const float*)d_in[6];
  const float* beta = (const float*)d_in[7];

  char* ws = (char*)d_ws;
  unsigned short* Kb  = (unsigned short*)(ws + 3145728);          // 4 MB
  unsigned short* Qb  = (unsigned short*)(ws + 7340032);          // 4 MB
  unsigned short* Vt  = (unsigned short*)(ws + 11534336);         // 4 MB
  unsigned short* Ob  = (unsigned short*)(ws + 15728640);         // 4 MB
  unsigned* ctr       = (unsigned*)(ws + 19922944);               // 64 B
  float* out = (float*)d_out;

  (void)hipMemsetAsync(ctr, 0, 64, stream);
  qkv_kernel<<<dim3(32, 4, 6), 256, 0, stream>>>(x, WK, WQ, WV, Kb, Qb, Vt);
  attn_kernel<<<dim3(512, 1, 1), 256, 0, stream>>>(Kb, Qb, Vt, Ob);
  proj_bn_kernel<<<dim3(64, 4, 2), 256, 0, stream>>>(Ob, Wo, bo, x, out,
                                                     gamma, beta, ctr);
}